// Round 1
// baseline (1082.302 us; speedup 1.0000x reference)
//
#include <hip/hip_runtime.h>

// out[n,o] = sum_s attn[s] * (X[s] @ W[s])[n,o] + bias[o]
// == GEMM: A[N=200000][K=1024] (X, fp32, k=(s,i)) x B[K][M=128] (attn-folded W)
// Strategy: prep kernel folds attn into W and converts to bf16 (tiled layout in
// d_ws), main kernel is a 128x128-tile bf16-MFMA GEMM converting X fp32->bf16
// during LDS staging. Memory-bound: floor ~146us (922 MB @ 6.3 TB/s).

typedef __bf16 bf16x8 __attribute__((ext_vector_type(8)));
typedef float  f32x4  __attribute__((ext_vector_type(4)));

#define N_DIM 200000
#define LDSS  72   // LDS row stride in bf16 elems (64 + 8 pad -> 2-way banks, free)

// Wt[((k>>6)*128 + o)*64 + (k&63)] = bf16(attn[k>>7] * W[k*128 + o]), k = s*128+i
__global__ void prep_w_kernel(const float* __restrict__ W,
                              const float* __restrict__ attn,
                              __bf16* __restrict__ Wt) {
    const int idx = blockIdx.x * 256 + threadIdx.x;   // 0..131071
    const int o = idx >> 10;                          // 0..127
    const int k = idx & 1023;                         // 0..1023
    const int s = k >> 7;
    const float v = attn[s] * W[(size_t)k * 128 + o];
    Wt[((size_t)(k >> 6) * 128 + o) * 64 + (k & 63)] = (__bf16)v;
}

__global__ __launch_bounds__(256, 2)
void mgc_kernel(const float* __restrict__ X,
                const __bf16* __restrict__ Wt,
                const float* __restrict__ bias,
                float* __restrict__ out) {
    __shared__ __bf16 As[128 * LDSS];   // 18 KiB
    __shared__ __bf16 Bs[128 * LDSS];   // 18 KiB

    const int tid  = threadIdx.x;
    const int lane = tid & 63;
    const int wave = tid >> 6;
    const int wr   = (wave >> 1) * 64;   // wave row offset in 128x128 tile
    const int wc   = (wave & 1) * 64;    // wave col offset
    const int l15  = lane & 15;
    const int quad = lane >> 4;

    const long n0 = (long)blockIdx.x * 128;

    f32x4 acc[4][4] = {};

    const int ara = tid >> 3;            // A staging: row base (0..31), 4 passes of 32 rows
    const int ack = (tid & 7) * 8;       // A staging: k offset (8 elems = 32B fp32 / 16B bf16)

    #pragma unroll 1
    for (int kb = 0; kb < 16; ++kb) {
        const int s  = kb >> 1;
        const int i0 = (kb & 1) * 64;
        const float*  Ablk = X  + ((size_t)s * N_DIM + (size_t)n0) * 128 + i0;
        const __bf16* Bblk = Wt + (size_t)kb * 8192;   // contiguous 16 KiB tile

        __syncthreads();   // protect LDS from prior iteration's readers

        // ---- stage A: 128 rows x 64 k, fp32 -> bf16, b128 LDS writes ----
        #pragma unroll
        for (int p = 0; p < 4; ++p) {
            const int r = ara + p * 32;
            f32x4 v0 = {0.f, 0.f, 0.f, 0.f}, v1 = {0.f, 0.f, 0.f, 0.f};
            if (n0 + r < N_DIM) {
                const f32x4* src = (const f32x4*)(Ablk + (size_t)r * 128 + ack);
                v0 = src[0];
                v1 = src[1];
            }
            bf16x8 w;
            w[0] = (__bf16)v0.x; w[1] = (__bf16)v0.y; w[2] = (__bf16)v0.z; w[3] = (__bf16)v0.w;
            w[4] = (__bf16)v1.x; w[5] = (__bf16)v1.y; w[6] = (__bf16)v1.z; w[7] = (__bf16)v1.w;
            *(bf16x8*)(&As[r * LDSS + ack]) = w;
        }

        // ---- stage B: 128 cols x 64 k, already bf16, contiguous coalesced copy ----
        #pragma unroll
        for (int j = 0; j < 4; ++j) {
            const int e = (j * 256 + tid) * 8;                   // elem offset in 8192-elem tile
            bf16x8 v = *(const bf16x8*)(Bblk + e);
            *(bf16x8*)(&Bs[(e >> 6) * LDSS + (e & 63)]) = v;     // Bs[col][k]
        }

        __syncthreads();

        // ---- compute: 2 k-steps x 16 MFMA ----
        #pragma unroll
        for (int kk = 0; kk < 64; kk += 32) {
            bf16x8 af[4], bfr[4];
            #pragma unroll
            for (int t = 0; t < 4; ++t)
                af[t] = *(const bf16x8*)(&As[(wr + t * 16 + l15) * LDSS + kk + quad * 8]);
            #pragma unroll
            for (int t = 0; t < 4; ++t)
                bfr[t] = *(const bf16x8*)(&Bs[(wc + t * 16 + l15) * LDSS + kk + quad * 8]);
            #pragma unroll
            for (int i = 0; i < 4; ++i)
                #pragma unroll
                for (int j = 0; j < 4; ++j)
                    acc[i][j] = __builtin_amdgcn_mfma_f32_16x16x32_bf16(af[i], bfr[j], acc[i][j], 0, 0, 0);
        }
    }

    // ---- epilogue: bias add + fp32 store (C/D layout: col=lane&15, row=quad*4+reg) ----
    float bv[4];
    #pragma unroll
    for (int j = 0; j < 4; ++j)
        bv[j] = bias[wc + j * 16 + l15];

    #pragma unroll
    for (int i = 0; i < 4; ++i) {
        #pragma unroll
        for (int reg = 0; reg < 4; ++reg) {
            const long r = n0 + wr + i * 16 + quad * 4 + reg;
            if (r < N_DIM) {
                float* orow = out + r * 128 + wc + l15;
                #pragma unroll
                for (int j = 0; j < 4; ++j)
                    orow[j * 16] = acc[i][j][reg] + bv[j];
            }
        }
    }
}

extern "C" void kernel_launch(void* const* d_in, const int* in_sizes, int n_in,
                              void* d_out, int out_size, void* d_ws, size_t ws_size,
                              hipStream_t stream) {
    const float* X    = (const float*)d_in[0];   // [8][200000][128]
    const float* W    = (const float*)d_in[1];   // [8][128][128]
    const float* attn = (const float*)d_in[2];   // [8]
    const float* bias = (const float*)d_in[3];   // [128]
    float* out = (float*)d_out;                  // [200000][128]
    __bf16* Wt = (__bf16*)d_ws;                  // needs 1024*128*2 = 256 KiB scratch

    prep_w_kernel<<<512, 256, 0, stream>>>(W, attn, Wt);
    const int nblocks = (N_DIM + 127) / 128;     // 1563 (last block: 64 valid rows)
    mgc_kernel<<<nblocks, 256, 0, stream>>>(X, Wt, bias, out);
}